// Round 3
// baseline (104.947 us; speedup 1.0000x reference)
//
#include <hip/hip_runtime.h>
#include <hip/hip_fp16.h>

typedef _Float16 half8 __attribute__((ext_vector_type(8)));
typedef float    f32x4 __attribute__((ext_vector_type(4)));

#define NF        64
#define HID       128
#define NPAIRS    31250   // 1M edges / 32 per pair (2 x 16-edge tiles)
#define RPAIRS    15625   // pairs in cliques_r (500000/32)
#define NFH_ELEMS 6400000 // 100000 * 64

// ---- pre-pass: node_features f32 -> fp16 ----
__global__ __launch_bounds__(256) void cvt_kernel(const float* __restrict__ nf,
                                                  _Float16* __restrict__ nfh)
{
    const long id = (long)blockIdx.x * 256 + threadIdx.x; // 8 elems each
    if (id >= NFH_ELEMS / 8) return;
    const float4 u = ((const float4*)nf)[id * 2 + 0];
    const float4 v = ((const float4*)nf)[id * 2 + 1];
    half8 h;
    h[0] = (_Float16)u.x; h[1] = (_Float16)u.y; h[2] = (_Float16)u.z; h[3] = (_Float16)u.w;
    h[4] = (_Float16)v.x; h[5] = (_Float16)v.y; h[6] = (_Float16)v.z; h[7] = (_Float16)v.w;
    ((half8*)nfh)[id] = h;
}

// ---- main kernel: 32 edges (2 tiles) per wave-iteration, W5 fragments in LDS ----
template <int PRE>
__global__ __launch_bounds__(256, 4) void edge_pred_kernel(
    const float*    __restrict__ nf,
    const _Float16* __restrict__ nfh,
    const int*      __restrict__ cr,
    const int*      __restrict__ cs,
    const float*    __restrict__ w5,
    const float*    __restrict__ b5,
    const float*    __restrict__ w6,
    const float*    __restrict__ b6,
    float*          __restrict__ out)
{
    // Per-lane W5 fragment table in LDS, shared by the block's 4 waves.
    // lfrag[f=(t<<1)|kb][lane][e] = (f16) W5[32*kb + 8*(lane>>4) + e][16*t + (lane&15)]
    // Identical fragment definition to the (verified-correct) R2 bfrag.
    __shared__ _Float16 lfrag[16][64][8];   // 16 KB

    const int tid  = threadIdx.x;
    const int lane = tid & 63;
    const int wid  = tid >> 6;
    const int i    = lane & 15;   // edge-in-tile / B col-in-tile
    const int g    = lane >> 4;   // lane group 0..3

    {   // one-time stage (strided scalar f32 loads; L2-resident after 1st block)
        const int l = tid & 63, fb = tid >> 6;
        const int li = l & 15, lg = l >> 4;
        for (int f = fb; f < 16; f += 4) {
            const int t = f >> 1, kb = f & 1;
            const int col = 16 * t + li;
            half8 v;
#pragma unroll
            for (int e = 0; e < 8; ++e)
                v[e] = (_Float16)w5[(32 * kb + 8 * lg + e) * HID + col];
            *(half8*)&lfrag[f][l][0] = v;
        }
    }
    __syncthreads();

    float b5r[8], wdr[8];
#pragma unroll
    for (int t = 0; t < 8; ++t) {
        const int col = 16 * t + i;
        b5r[t] = b5[col];
        wdr[t] = w6[2 * col] - w6[2 * col + 1];   // W6[:,0]-W6[:,1]
    }
    const float bdiff = b6[0] - b6[1];

    const int gw = blockIdx.x * 4 + wid;
    const int nw = gridDim.x * 4;
    if (gw >= NPAIRS) return;

    auto clqpair = [&](int p, int2& c0, int2& c1) {
        p = (p < NPAIRS) ? p : (NPAIRS - 1);          // clamp for prefetch tail
        const int* cl  = (p < RPAIRS) ? cr : cs;
        const long e0  = (long)((p < RPAIRS) ? p : p - RPAIRS) * 32 + i;
        c0 = *(const int2*)(cl + e0 * 4);             // clique cols 0,1 (tile u=0)
        c1 = *(const int2*)(cl + (e0 + 16) * 4);      // tile u=1
    };
    auto gather1 = [&](int2 ix, half8& x0, half8& x1, half8& y0, half8& y1) {
        if constexpr (PRE) {
            const _Float16* p0 = nfh + (long)ix.x * NF;
            const _Float16* p1 = nfh + (long)ix.y * NF;
            x0 = *(const half8*)(p0 + 8 * g);         // node0, k in [8g, 8g+8)
            x1 = *(const half8*)(p0 + 32 + 8 * g);    // node0, k in [32+8g, ...)
            y0 = *(const half8*)(p1 + 8 * g);
            y1 = *(const half8*)(p1 + 32 + 8 * g);
        } else {
            const float* p0 = nf + (long)ix.x * NF;
            const float* p1 = nf + (long)ix.y * NF;
            const float4 a = *(const float4*)(p0 + 8 * g);
            const float4 b = *(const float4*)(p0 + 8 * g + 4);
            const float4 c = *(const float4*)(p0 + 32 + 8 * g);
            const float4 d = *(const float4*)(p0 + 32 + 8 * g + 4);
            const float4 e = *(const float4*)(p1 + 8 * g);
            const float4 f = *(const float4*)(p1 + 8 * g + 4);
            const float4 m = *(const float4*)(p1 + 32 + 8 * g);
            const float4 n = *(const float4*)(p1 + 32 + 8 * g + 4);
            x0[0]=(_Float16)a.x; x0[1]=(_Float16)a.y; x0[2]=(_Float16)a.z; x0[3]=(_Float16)a.w;
            x0[4]=(_Float16)b.x; x0[5]=(_Float16)b.y; x0[6]=(_Float16)b.z; x0[7]=(_Float16)b.w;
            x1[0]=(_Float16)c.x; x1[1]=(_Float16)c.y; x1[2]=(_Float16)c.z; x1[3]=(_Float16)c.w;
            x1[4]=(_Float16)d.x; x1[5]=(_Float16)d.y; x1[6]=(_Float16)d.z; x1[7]=(_Float16)d.w;
            y0[0]=(_Float16)e.x; y0[1]=(_Float16)e.y; y0[2]=(_Float16)e.z; y0[3]=(_Float16)e.w;
            y0[4]=(_Float16)f.x; y0[5]=(_Float16)f.y; y0[6]=(_Float16)f.z; y0[7]=(_Float16)f.w;
            y1[0]=(_Float16)m.x; y1[1]=(_Float16)m.y; y1[2]=(_Float16)m.z; y1[3]=(_Float16)m.w;
            y1[4]=(_Float16)n.x; y1[5]=(_Float16)n.y; y1[6]=(_Float16)n.z; y1[7]=(_Float16)n.w;
        }
    };

    // ---- pipeline: current-pair data in d[8]; next-pair idx prefetched ----
    int2 ix0, ix1, ixn0, ixn1;
    half8 d[8];
    clqpair(gw, ix0, ix1);
    gather1(ix0, d[0], d[1], d[2], d[3]);
    gather1(ix1, d[4], d[5], d[6], d[7]);
    clqpair(gw + nw, ixn0, ixn1);

    for (int p = gw; p < NPAIRS; p += nw) {
        // products (A fragments) for the two tiles of this pair
        const half8 a00 = d[0] * d[2];   // u=0, k in [0,32)
        const half8 a01 = d[1] * d[3];   // u=0, k in [32,64)
        const half8 a10 = d[4] * d[6];   // u=1
        const half8 a11 = d[5] * d[7];

        // prefetch next pair: overwrite d, then refresh idx (2-deep)
        gather1(ixn0, d[0], d[1], d[2], d[3]);
        gather1(ixn1, d[4], d[5], d[6], d[7]);
        clqpair(p + 2 * nw, ixn0, ixn1);

        // t-loop: each LDS fragment read feeds BOTH tiles (2 MFMAs per read)
        float su[2][4] = {{0.f,0.f,0.f,0.f},{0.f,0.f,0.f,0.f}};
#pragma unroll
        for (int t = 0; t < 8; ++t) {
            const half8 bf0 = *(const half8*)&lfrag[2 * t + 0][lane][0];
            const half8 bf1 = *(const half8*)&lfrag[2 * t + 1][lane][0];
            f32x4 z0 = {0.f,0.f,0.f,0.f}, z1 = {0.f,0.f,0.f,0.f};
            z0 = __builtin_amdgcn_mfma_f32_16x16x32_f16(a00, bf0, z0, 0, 0, 0);
            z0 = __builtin_amdgcn_mfma_f32_16x16x32_f16(a01, bf1, z0, 0, 0, 0);
            z1 = __builtin_amdgcn_mfma_f32_16x16x32_f16(a10, bf0, z1, 0, 0, 0);
            z1 = __builtin_amdgcn_mfma_f32_16x16x32_f16(a11, bf1, z1, 0, 0, 0);
#pragma unroll
            for (int r = 0; r < 4; ++r) {
                const float h0 = fmaxf(z0[r] + b5r[t], 0.f);
                const float h1 = fmaxf(z1[r] + b5r[t], 0.f);
                su[0][r] = fmaf(h0, wdr[t], su[0][r]);
                su[1][r] = fmaf(h1, wdr[t], su[1][r]);
            }
        }

        // 16-lane (i) butterfly reduce per row; rows are edges 4g+r
#pragma unroll
        for (int u = 0; u < 2; ++u)
#pragma unroll
            for (int r = 0; r < 4; ++r) {
                float a_ = su[u][r];
                a_ += __shfl_xor(a_, 1);
                a_ += __shfl_xor(a_, 2);
                a_ += __shfl_xor(a_, 4);
                a_ += __shfl_xor(a_, 8);
                su[u][r] = a_;
            }

        if (i < 8) {
            const int r = i >> 1, c = i & 1;
#pragma unroll
            for (int u = 0; u < 2; ++u) {
                // static-index select (avoid runtime-indexed array -> scratch)
                const float sv = (r == 0) ? su[u][0] : (r == 1) ? su[u][1]
                               : (r == 2) ? su[u][2] : su[u][3];
                const float z  = sv + bdiff;
                const float pz = 1.0f / (1.0f + __expf(-z));
                const long tile = 2L * p + u;
                out[tile * 32 + 8 * g + i] = c ? (1.0f - pz) : pz;
            }
        }
    }
}

extern "C" void kernel_launch(void* const* d_in, const int* in_sizes, int n_in,
                              void* d_out, int out_size, void* d_ws, size_t ws_size,
                              hipStream_t stream) {
    const float* nf = (const float*)d_in[3];   // node_features (d_in[0] 'x' unused by ref)
    const int*   cr = (const int*)d_in[1];
    const int*   cs = (const int*)d_in[2];
    const float* w5 = (const float*)d_in[4];
    const float* b5 = (const float*)d_in[5];
    const float* w6 = (const float*)d_in[6];
    const float* b6 = (const float*)d_in[7];
    float* out = (float*)d_out;

    if (ws_size >= (size_t)NFH_ELEMS * 2) {
        _Float16* nfh = (_Float16*)d_ws;
        hipLaunchKernelGGL(cvt_kernel, dim3(NFH_ELEMS / 8 / 256), dim3(256), 0, stream,
                           nf, nfh);
        hipLaunchKernelGGL((edge_pred_kernel<1>), dim3(1024), dim3(256), 0, stream,
                           nf, nfh, cr, cs, w5, b5, w6, b6, out);
    } else {
        hipLaunchKernelGGL((edge_pred_kernel<0>), dim3(1024), dim3(256), 0, stream,
                           nf, (const _Float16*)nullptr, cr, cs, w5, b5, w6, b6, out);
    }
}

// Round 4
// 56.813 us; speedup vs baseline: 1.8472x; 1.8472x over previous
//
#include <hip/hip_runtime.h>
#include <hip/hip_fp16.h>

typedef _Float16 half8 __attribute__((ext_vector_type(8)));
typedef float    f32x4 __attribute__((ext_vector_type(4)));

#define NF        64
#define HID       128
#define NPAIRS    31250   // 1M edges / 32 per pair (2 x 16-edge tiles)
#define RPAIRS    15625   // pairs in cliques_r (500000/32)
#define NFH_ELEMS 6400000 // 100000 * 64

// ---- pre-pass: node_features f32 -> fp16 ----
__global__ __launch_bounds__(256) void cvt_kernel(const float* __restrict__ nf,
                                                  _Float16* __restrict__ nfh)
{
    const long id = (long)blockIdx.x * 256 + threadIdx.x; // 8 elems each
    if (id >= NFH_ELEMS / 8) return;
    const float4 u = ((const float4*)nf)[id * 2 + 0];
    const float4 v = ((const float4*)nf)[id * 2 + 1];
    half8 h;
    h[0] = (_Float16)u.x; h[1] = (_Float16)u.y; h[2] = (_Float16)u.z; h[3] = (_Float16)u.w;
    h[4] = (_Float16)v.x; h[5] = (_Float16)v.y; h[6] = (_Float16)v.z; h[7] = (_Float16)v.w;
    ((half8*)nfh)[id] = h;
}

// ---- main kernel: 32 edges (2 tiles) per wave-iteration, W5 fragments in LDS ----
// NOTE: plain __launch_bounds__(256). The (256,4) min-occupancy clause capped the
// allocator at 64 VGPRs -> ~43 MB/launch of scratch spills (R3: WRITE_SIZE 51 MB,
// VALUBusy 0.7%). Working set needs ~110 VGPRs; let the allocator have them.
template <int PRE>
__global__ __launch_bounds__(256) void edge_pred_kernel(
    const float*    __restrict__ nf,
    const _Float16* __restrict__ nfh,
    const int*      __restrict__ cr,
    const int*      __restrict__ cs,
    const float*    __restrict__ w5,
    const float*    __restrict__ b5,
    const float*    __restrict__ w6,
    const float*    __restrict__ b6,
    float*          __restrict__ out)
{
    // Per-lane W5 fragment table in LDS, shared by the block's 4 waves.
    // lfrag[f=(t<<1)|kb][lane][e] = (f16) W5[32*kb + 8*(lane>>4) + e][16*t + (lane&15)]
    // (verified-correct fragment definition from R2/R3; ds_read_b128 conflict-free,
    //  SQ_LDS_BANK_CONFLICT measured 0)
    __shared__ _Float16 lfrag[16][64][8];   // 16 KB

    const int tid  = threadIdx.x;
    const int lane = tid & 63;
    const int wid  = tid >> 6;
    const int i    = lane & 15;   // edge-in-tile / B col-in-tile
    const int g    = lane >> 4;   // lane group 0..3

    {   // one-time stage (strided scalar f32 loads; L2-resident after 1st block)
        const int l = tid & 63, fb = tid >> 6;
        const int li = l & 15, lg = l >> 4;
        for (int f = fb; f < 16; f += 4) {
            const int t = f >> 1, kb = f & 1;
            const int col = 16 * t + li;
            half8 v;
#pragma unroll
            for (int e = 0; e < 8; ++e)
                v[e] = (_Float16)w5[(32 * kb + 8 * lg + e) * HID + col];
            *(half8*)&lfrag[f][l][0] = v;
        }
    }
    __syncthreads();

    float b5r[8], wdr[8];
#pragma unroll
    for (int t = 0; t < 8; ++t) {
        const int col = 16 * t + i;
        b5r[t] = b5[col];
        wdr[t] = w6[2 * col] - w6[2 * col + 1];   // W6[:,0]-W6[:,1]
    }
    const float bdiff = b6[0] - b6[1];

    const int gw = blockIdx.x * 4 + wid;
    const int nw = gridDim.x * 4;
    if (gw >= NPAIRS) return;

    auto clqpair = [&](int p, int2& c0, int2& c1) {
        p = (p < NPAIRS) ? p : (NPAIRS - 1);          // clamp for prefetch tail
        const int* cl  = (p < RPAIRS) ? cr : cs;
        const long e0  = (long)((p < RPAIRS) ? p : p - RPAIRS) * 32 + i;
        c0 = *(const int2*)(cl + e0 * 4);             // clique cols 0,1 (tile u=0)
        c1 = *(const int2*)(cl + (e0 + 16) * 4);      // tile u=1
    };
    auto gather1 = [&](int2 ix, half8& x0, half8& x1, half8& y0, half8& y1) {
        if constexpr (PRE) {
            const _Float16* p0 = nfh + (long)ix.x * NF;
            const _Float16* p1 = nfh + (long)ix.y * NF;
            x0 = *(const half8*)(p0 + 8 * g);         // node0, k in [8g, 8g+8)
            x1 = *(const half8*)(p0 + 32 + 8 * g);    // node0, k in [32+8g, ...)
            y0 = *(const half8*)(p1 + 8 * g);
            y1 = *(const half8*)(p1 + 32 + 8 * g);
        } else {
            const float* p0 = nf + (long)ix.x * NF;
            const float* p1 = nf + (long)ix.y * NF;
            const float4 a = *(const float4*)(p0 + 8 * g);
            const float4 b = *(const float4*)(p0 + 8 * g + 4);
            const float4 c = *(const float4*)(p0 + 32 + 8 * g);
            const float4 d = *(const float4*)(p0 + 32 + 8 * g + 4);
            const float4 e = *(const float4*)(p1 + 8 * g);
            const float4 f = *(const float4*)(p1 + 8 * g + 4);
            const float4 m = *(const float4*)(p1 + 32 + 8 * g);
            const float4 n = *(const float4*)(p1 + 32 + 8 * g + 4);
            x0[0]=(_Float16)a.x; x0[1]=(_Float16)a.y; x0[2]=(_Float16)a.z; x0[3]=(_Float16)a.w;
            x0[4]=(_Float16)b.x; x0[5]=(_Float16)b.y; x0[6]=(_Float16)b.z; x0[7]=(_Float16)b.w;
            x1[0]=(_Float16)c.x; x1[1]=(_Float16)c.y; x1[2]=(_Float16)c.z; x1[3]=(_Float16)c.w;
            x1[4]=(_Float16)d.x; x1[5]=(_Float16)d.y; x1[6]=(_Float16)d.z; x1[7]=(_Float16)d.w;
            y0[0]=(_Float16)e.x; y0[1]=(_Float16)e.y; y0[2]=(_Float16)e.z; y0[3]=(_Float16)e.w;
            y0[4]=(_Float16)f.x; y0[5]=(_Float16)f.y; y0[6]=(_Float16)f.z; y0[7]=(_Float16)f.w;
            y1[0]=(_Float16)m.x; y1[1]=(_Float16)m.y; y1[2]=(_Float16)m.z; y1[3]=(_Float16)m.w;
            y1[4]=(_Float16)n.x; y1[5]=(_Float16)n.y; y1[6]=(_Float16)n.z; y1[7]=(_Float16)n.w;
        }
    };

    // ---- pipeline: current-pair data in d[8]; next-pair idx prefetched ----
    int2 ix0, ix1, ixn0, ixn1;
    half8 d[8];
    clqpair(gw, ix0, ix1);
    gather1(ix0, d[0], d[1], d[2], d[3]);
    gather1(ix1, d[4], d[5], d[6], d[7]);
    clqpair(gw + nw, ixn0, ixn1);

    for (int p = gw; p < NPAIRS; p += nw) {
        // products (A fragments) for the two tiles of this pair
        const half8 a00 = d[0] * d[2];   // u=0, k in [0,32)
        const half8 a01 = d[1] * d[3];   // u=0, k in [32,64)
        const half8 a10 = d[4] * d[6];   // u=1
        const half8 a11 = d[5] * d[7];

        // prefetch next pair: overwrite d, then refresh idx (2-deep)
        gather1(ixn0, d[0], d[1], d[2], d[3]);
        gather1(ixn1, d[4], d[5], d[6], d[7]);
        clqpair(p + 2 * nw, ixn0, ixn1);

        // t-loop: each LDS fragment read feeds BOTH tiles (2 MFMAs per read)
        float su[2][4] = {{0.f,0.f,0.f,0.f},{0.f,0.f,0.f,0.f}};
#pragma unroll
        for (int t = 0; t < 8; ++t) {
            const half8 bf0 = *(const half8*)&lfrag[2 * t + 0][lane][0];
            const half8 bf1 = *(const half8*)&lfrag[2 * t + 1][lane][0];
            f32x4 z0 = {0.f,0.f,0.f,0.f}, z1 = {0.f,0.f,0.f,0.f};
            z0 = __builtin_amdgcn_mfma_f32_16x16x32_f16(a00, bf0, z0, 0, 0, 0);
            z0 = __builtin_amdgcn_mfma_f32_16x16x32_f16(a01, bf1, z0, 0, 0, 0);
            z1 = __builtin_amdgcn_mfma_f32_16x16x32_f16(a10, bf0, z1, 0, 0, 0);
            z1 = __builtin_amdgcn_mfma_f32_16x16x32_f16(a11, bf1, z1, 0, 0, 0);
#pragma unroll
            for (int r = 0; r < 4; ++r) {
                const float h0 = fmaxf(z0[r] + b5r[t], 0.f);
                const float h1 = fmaxf(z1[r] + b5r[t], 0.f);
                su[0][r] = fmaf(h0, wdr[t], su[0][r]);
                su[1][r] = fmaf(h1, wdr[t], su[1][r]);
            }
        }

        // 16-lane (i) butterfly reduce per row; rows are edges 4g+r
#pragma unroll
        for (int u = 0; u < 2; ++u)
#pragma unroll
            for (int r = 0; r < 4; ++r) {
                float a_ = su[u][r];
                a_ += __shfl_xor(a_, 1);
                a_ += __shfl_xor(a_, 2);
                a_ += __shfl_xor(a_, 4);
                a_ += __shfl_xor(a_, 8);
                su[u][r] = a_;
            }

        if (i < 8) {
            const int r = i >> 1, c = i & 1;
#pragma unroll
            for (int u = 0; u < 2; ++u) {
                // static-index select (avoid runtime-indexed array -> scratch)
                const float sv = (r == 0) ? su[u][0] : (r == 1) ? su[u][1]
                               : (r == 2) ? su[u][2] : su[u][3];
                const float z  = sv + bdiff;
                const float pz = 1.0f / (1.0f + __expf(-z));
                const long tile = 2L * p + u;
                out[tile * 32 + 8 * g + i] = c ? (1.0f - pz) : pz;
            }
        }
    }
}

extern "C" void kernel_launch(void* const* d_in, const int* in_sizes, int n_in,
                              void* d_out, int out_size, void* d_ws, size_t ws_size,
                              hipStream_t stream) {
    const float* nf = (const float*)d_in[3];   // node_features (d_in[0] 'x' unused by ref)
    const int*   cr = (const int*)d_in[1];
    const int*   cs = (const int*)d_in[2];
    const float* w5 = (const float*)d_in[4];
    const float* b5 = (const float*)d_in[5];
    const float* w6 = (const float*)d_in[6];
    const float* b6 = (const float*)d_in[7];
    float* out = (float*)d_out;

    if (ws_size >= (size_t)NFH_ELEMS * 2) {
        _Float16* nfh = (_Float16*)d_ws;
        hipLaunchKernelGGL(cvt_kernel, dim3(NFH_ELEMS / 8 / 256), dim3(256), 0, stream,
                           nf, nfh);
        hipLaunchKernelGGL((edge_pred_kernel<1>), dim3(1024), dim3(256), 0, stream,
                           nf, nfh, cr, cs, w5, b5, w6, b6, out);
    } else {
        hipLaunchKernelGGL((edge_pred_kernel<0>), dim3(1024), dim3(256), 0, stream,
                           nf, (const _Float16*)nullptr, cr, cs, w5, b5, w6, b6, out);
    }
}